// Round 2
// baseline (275.836 us; speedup 1.0000x reference)
//
#include <hip/hip_runtime.h>
#include <hip/hip_bf16.h>

#define NN 20000
#define GG 128

__device__ __forceinline__ float silu_f(float v) {
    return v / (1.0f + expf(-v));
}

// ---------------------------------------------------------------------------
// Kernel 1: per-graph pipeline.  One block per graph, 128 threads.
// gadd[g][d] = 6 * ( ((cond_g @ Wv) @ Wo)[d] + bo[d] + silu(te_mlp_g[d]) )
// ---------------------------------------------------------------------------
__global__ __launch_bounds__(128) void graph_kernel(
        const float* __restrict__ t, const float* __restrict__ topo,
        const float* __restrict__ stab, const float* __restrict__ sust,
        const float* __restrict__ tmW1, const float* __restrict__ tmb1,
        const float* __restrict__ tmW2, const float* __restrict__ tmb2,
        const float* __restrict__ topoW1, const float* __restrict__ topob1,
        const float* __restrict__ topoW2, const float* __restrict__ topob2,
        const float* __restrict__ stabW1, const float* __restrict__ stabb1,
        const float* __restrict__ stabW2, const float* __restrict__ stabb2,
        const float* __restrict__ sustW1, const float* __restrict__ sustb1,
        const float* __restrict__ sustW2, const float* __restrict__ sustb2,
        const float* __restrict__ combW1, const float* __restrict__ combb1,
        const float* __restrict__ combW2, const float* __restrict__ combb2,
        const float* __restrict__ Wv, const float* __restrict__ Wo,
        const float* __restrict__ bo,
        float* __restrict__ gadd) {
    __shared__ float s_te[128];
    __shared__ float s_th1[256];
    __shared__ float s_tef[128];
    __shared__ float s_l1[64];
    __shared__ float s_cat[64];
    __shared__ float s_c1[64];
    __shared__ float s_cond[64];
    __shared__ float s_v[128];

    const int g = blockIdx.x;
    const int tid = threadIdx.x;

    // sinusoidal time embedding: freq_i = exp(-i * log(10000)/63)
    {
        const float tval = t[g];
        const int i = tid & 63;
        const float fr = expf(-(float)i * 0.14619587892025688f);
        const float arg = tval * fr;
        s_te[tid] = (tid < 64) ? sinf(arg) : cosf(arg);
    }
    __syncthreads();

    // time MLP layer 1: [128] -> [256], silu
    for (int j = tid; j < 256; j += 128) {
        float acc = tmb1[j];
        for (int k = 0; k < 128; ++k)
            acc += s_te[k] * tmW1[k * 256 + j];
        s_th1[j] = silu_f(acc);
    }
    __syncthreads();

    // time MLP layer 2: [256] -> [128]   (silu applied at use)
    {
        float acc = tmb2[tid];
        for (int k = 0; k < 256; ++k)
            acc += s_th1[k] * tmW2[k * 128 + tid];
        s_tef[tid] = acc;
    }

    // conditioning MLPs, layer 1
    if (tid < 32) {
        float acc = topob1[tid];
        for (int k = 0; k < 7; ++k)
            acc += topo[g * 7 + k] * topoW1[k * 32 + tid];
        s_l1[tid] = silu_f(acc);
    } else if (tid < 48) {
        const int j = tid - 32;
        float acc = stabb1[j];
        for (int k = 0; k < 2; ++k)
            acc += stab[g * 2 + k] * stabW1[k * 16 + j];
        s_l1[tid] = silu_f(acc);
    } else if (tid < 64) {
        const int j = tid - 48;
        float acc = sustb1[j];
        for (int k = 0; k < 3; ++k)
            acc += sust[g * 3 + k] * sustW1[k * 16 + j];
        s_l1[tid] = silu_f(acc);
    }
    __syncthreads();

    // conditioning MLPs, layer 2 -> concat[64]
    if (tid < 32) {
        float acc = topob2[tid];
        for (int k = 0; k < 32; ++k)
            acc += s_l1[k] * topoW2[k * 32 + tid];
        s_cat[tid] = acc;
    } else if (tid < 48) {
        const int j = tid - 32;
        float acc = stabb2[j];
        for (int k = 0; k < 16; ++k)
            acc += s_l1[32 + k] * stabW2[k * 16 + j];
        s_cat[tid] = acc;
    } else if (tid < 64) {
        const int j = tid - 48;
        float acc = sustb2[j];
        for (int k = 0; k < 16; ++k)
            acc += s_l1[48 + k] * sustW2[k * 16 + j];
        s_cat[tid] = acc;
    }
    __syncthreads();

    // comb MLP layer 1: [64] -> [64], silu
    if (tid < 64) {
        float acc = combb1[tid];
        for (int k = 0; k < 64; ++k)
            acc += s_cat[k] * combW1[k * 64 + tid];
        s_c1[tid] = silu_f(acc);
    }
    __syncthreads();

    // comb MLP layer 2: [64] -> [64]  (cond vector)
    if (tid < 64) {
        float acc = combb2[tid];
        for (int k = 0; k < 64; ++k)
            acc += s_c1[k] * combW2[k * 64 + tid];
        s_cond[tid] = acc;
    }
    __syncthreads();

    // v = cond @ Wv   [64] x [64,128] -> [128]
    {
        float acc = 0.0f;
        for (int k = 0; k < 64; ++k)
            acc += s_cond[k] * Wv[k * 128 + tid];
        s_v[tid] = acc;
    }
    __syncthreads();

    // a = v @ Wo + bo ; gadd = 6*(a + silu(te))
    {
        float acc = bo[tid];
        for (int k = 0; k < 128; ++k)
            acc += s_v[k] * Wo[k * 128 + tid];
        gadd[g * 128 + tid] = 6.0f * (acc + silu_f(s_tef[tid]));
    }
}

// ---------------------------------------------------------------------------
// Kernel 2: per-node output MLPs.  64 nodes per block, 256 threads (4 waves).
// lane = node-in-tile; each wave owns a 64-column slice of the 256-wide hidden.
// ---------------------------------------------------------------------------
#define BN 64

__global__ __launch_bounds__(256) void node_kernel(
        const float* __restrict__ x, const int* __restrict__ batch,
        const float* __restrict__ Wn, const float* __restrict__ bn,
        const float* __restrict__ npW1, const float* __restrict__ npb1,
        const float* __restrict__ npW2, const float* __restrict__ npb2,
        const float* __restrict__ ppW1, const float* __restrict__ ppb1,
        const float* __restrict__ ppW2, const float* __restrict__ ppb2,
        const float* __restrict__ gadd,
        float* __restrict__ out) {
    __shared__ float h_s[BN * 129];      // row stride 129: 2-way bank alias (free)
    __shared__ float red_s[4 * BN * 12]; // cross-wave partial-sum buffer

    const int nb = blockIdx.x * BN;

    // ---- phase 1: h[n][d] = bn[d] + gadd[batch[n]][d] + sum_k x[n][k]*Wn[k][d]
    for (int idx = threadIdx.x; idx < BN * 128; idx += 256) {
        const int nl = idx >> 7;
        const int d  = idx & 127;
        const int gn = nb + nl;
        float acc = 0.0f;
        if (gn < NN) {
            const int b = batch[gn];
            acc = bn[d] + gadd[b * 128 + d];
#pragma unroll
            for (int k = 0; k < 12; ++k)
                acc += x[gn * 12 + k] * Wn[k * 128 + d];
        }
        h_s[nl * 129 + d] = acc;
    }
    __syncthreads();

    const int wave = threadIdx.x >> 6;
    const int lane = threadIdx.x & 63;
    const int jbase = __builtin_amdgcn_readfirstlane((threadIdx.x >> 6) << 6);

    // ---- phase 2: node_pred = silu(h @ npW1 + b1) @ npW2 + b2
    {
        float acc[64];
#pragma unroll
        for (int jj = 0; jj < 64; ++jj) acc[jj] = npb1[jbase + jj];
        for (int k = 0; k < 128; ++k) {
            const float hk = h_s[lane * 129 + k];
            const float* wr = npW1 + k * 256 + jbase;
#pragma unroll
            for (int jj = 0; jj < 64; ++jj) acc[jj] += hk * wr[jj];
        }
        float pout[12];
#pragma unroll
        for (int o = 0; o < 12; ++o) pout[o] = 0.0f;
#pragma unroll
        for (int jj = 0; jj < 64; ++jj) {
            const float zv = silu_f(acc[jj]);
            const float* w2 = npW2 + (jbase + jj) * 12;
#pragma unroll
            for (int o = 0; o < 12; ++o) pout[o] += zv * w2[o];
        }
#pragma unroll
        for (int o = 0; o < 12; ++o) red_s[(wave * BN + lane) * 12 + o] = pout[o];
    }
    __syncthreads();

    for (int idx = threadIdx.x; idx < BN * 12; idx += 256) {
        const int nl = idx / 12;
        const int o  = idx - nl * 12;
        float v = npb2[o];
#pragma unroll
        for (int w = 0; w < 4; ++w) v += red_s[(w * BN + nl) * 12 + o];
        const int gn = nb + nl;
        if (gn < NN) out[gn * 12 + o] = v;
    }
    __syncthreads();

    // ---- phase 3: pos_pred = silu(h @ ppW1 + b1) @ ppW2 + b2
    {
        const int j2 = jbase >> 1;  // 0,32,64,96
        float acc2[32];
#pragma unroll
        for (int jj = 0; jj < 32; ++jj) acc2[jj] = ppb1[j2 + jj];
        for (int k = 0; k < 128; ++k) {
            const float hk = h_s[lane * 129 + k];
            const float* wr = ppW1 + k * 128 + j2;
#pragma unroll
            for (int jj = 0; jj < 32; ++jj) acc2[jj] += hk * wr[jj];
        }
        float pout[3] = {0.0f, 0.0f, 0.0f};
#pragma unroll
        for (int jj = 0; jj < 32; ++jj) {
            const float zv = silu_f(acc2[jj]);
            const float* w2 = ppW2 + (j2 + jj) * 3;
#pragma unroll
            for (int o = 0; o < 3; ++o) pout[o] += zv * w2[o];
        }
#pragma unroll
        for (int o = 0; o < 3; ++o) red_s[(wave * BN + lane) * 3 + o] = pout[o];
    }
    __syncthreads();

    for (int idx = threadIdx.x; idx < BN * 3; idx += 256) {
        const int nl = idx / 3;
        const int o  = idx - nl * 3;
        float v = ppb2[o];
#pragma unroll
        for (int w = 0; w < 4; ++w) v += red_s[(w * BN + nl) * 3 + o];
        const int gn = nb + nl;
        if (gn < NN) out[NN * 12 + gn * 3 + o] = v;
    }
}

// ---------------------------------------------------------------------------
extern "C" void kernel_launch(void* const* d_in, const int* in_sizes, int n_in,
                              void* d_out, int out_size, void* d_ws, size_t ws_size,
                              hipStream_t stream) {
    const float* x      = (const float*)d_in[0];
    const float* t      = (const float*)d_in[4];
    const float* topo   = (const float*)d_in[5];
    const float* stab   = (const float*)d_in[6];
    const float* sust   = (const float*)d_in[7];
    const int*   batch  = (const int*)d_in[8];
    const float* Wn     = (const float*)d_in[9];
    const float* bn     = (const float*)d_in[10];
    const float* tmW1   = (const float*)d_in[13];
    const float* tmb1   = (const float*)d_in[14];
    const float* tmW2   = (const float*)d_in[15];
    const float* tmb2   = (const float*)d_in[16];
    const float* topoW1 = (const float*)d_in[17];
    const float* topob1 = (const float*)d_in[18];
    const float* topoW2 = (const float*)d_in[19];
    const float* topob2 = (const float*)d_in[20];
    const float* stabW1 = (const float*)d_in[21];
    const float* stabb1 = (const float*)d_in[22];
    const float* stabW2 = (const float*)d_in[23];
    const float* stabb2 = (const float*)d_in[24];
    const float* sustW1 = (const float*)d_in[25];
    const float* sustb1 = (const float*)d_in[26];
    const float* sustW2 = (const float*)d_in[27];
    const float* sustb2 = (const float*)d_in[28];
    const float* combW1 = (const float*)d_in[29];
    const float* combb1 = (const float*)d_in[30];
    const float* combW2 = (const float*)d_in[31];
    const float* combb2 = (const float*)d_in[32];
    const float* Wv     = (const float*)d_in[35];
    const float* Wo     = (const float*)d_in[36];
    const float* bo     = (const float*)d_in[37];
    const float* npW1   = (const float*)d_in[44];
    const float* npb1   = (const float*)d_in[45];
    const float* npW2   = (const float*)d_in[46];
    const float* npb2   = (const float*)d_in[47];
    const float* ppW1   = (const float*)d_in[48];
    const float* ppb1   = (const float*)d_in[49];
    const float* ppW2   = (const float*)d_in[50];
    const float* ppb2   = (const float*)d_in[51];

    float* gadd = (float*)d_ws;    // 128*128 floats
    float* out  = (float*)d_out;

    // 1) per-graph additive vector
    graph_kernel<<<GG, 128, 0, stream>>>(t, topo, stab, sust,
                                         tmW1, tmb1, tmW2, tmb2,
                                         topoW1, topob1, topoW2, topob2,
                                         stabW1, stabb1, stabW2, stabb2,
                                         sustW1, sustb1, sustW2, sustb2,
                                         combW1, combb1, combW2, combb2,
                                         Wv, Wo, bo, gadd);
    // 2) per-node output MLPs
    node_kernel<<<(NN + BN - 1) / BN, 256, 0, stream>>>(
        x, batch, Wn, bn, npW1, npb1, npW2, npb2,
        ppW1, ppb1, ppW2, ppb2, gadd, out);
}

// Round 3
// 234.181 us; speedup vs baseline: 1.1779x; 1.1779x over previous
//
#include <hip/hip_runtime.h>
#include <hip/hip_bf16.h>

#define NN 20000
#define GG 128
#define BN 64

typedef __bf16 bf16x8_t __attribute__((ext_vector_type(8)));
typedef float  f32x4_t  __attribute__((ext_vector_type(4)));
typedef __hip_bfloat16 hbf16;

// ws layout (bf16-element offsets from (hbf16*)d_ws):
//   bytes [0, 65536)  : gadd fp32 [128][128]
#define PK_NPW1 32768   // 32768 bf16 : npW1 packed B-fragments (16 ct x 4 kb x 64 lane x 8)
#define PK_PPW1 65536   // 16384 bf16 : ppW1 packed (8 ct x 4 kb x 64 x 8)
#define PK_NPW2 81920   //  4096 bf16 : npW2 packed (8 kb x 64 x 8), cols>=12 zero
#define PK_PPW2 86016   //  2048 bf16 : ppW2 packed (4 kb x 64 x 8), cols>=3 zero

__device__ __forceinline__ float silu_f(float v) {
    return v / (1.0f + expf(-v));
}

// ---------------------------------------------------------------------------
// Kernel 1: per-graph pipeline + weight fragment packing.
// 128 blocks x 256 threads.
// gadd[g][d] = 6 * ( ((cond_g @ Wv) @ Wo)[d] + bo[d] + silu(te_mlp_g[d]) )
// ---------------------------------------------------------------------------
__global__ __launch_bounds__(256) void graph_kernel(
        const float* __restrict__ t, const float* __restrict__ topo,
        const float* __restrict__ stab, const float* __restrict__ sust,
        const float* __restrict__ tmW1, const float* __restrict__ tmb1,
        const float* __restrict__ tmW2, const float* __restrict__ tmb2,
        const float* __restrict__ topoW1, const float* __restrict__ topob1,
        const float* __restrict__ topoW2, const float* __restrict__ topob2,
        const float* __restrict__ stabW1, const float* __restrict__ stabb1,
        const float* __restrict__ stabW2, const float* __restrict__ stabb2,
        const float* __restrict__ sustW1, const float* __restrict__ sustb1,
        const float* __restrict__ sustW2, const float* __restrict__ sustb2,
        const float* __restrict__ combW1, const float* __restrict__ combb1,
        const float* __restrict__ combW2, const float* __restrict__ combb2,
        const float* __restrict__ Wv, const float* __restrict__ Wo,
        const float* __restrict__ bo,
        const float* __restrict__ npW1, const float* __restrict__ npW2,
        const float* __restrict__ ppW1, const float* __restrict__ ppW2,
        float* __restrict__ gadd, hbf16* __restrict__ wsb) {
    __shared__ float s_te[128];
    __shared__ float s_th1[256];
    __shared__ float s_tef[128];
    __shared__ float s_l1[64];
    __shared__ float s_cat[64];
    __shared__ float s_c1[64];
    __shared__ float s_cond[64];
    __shared__ float s_v[128];
    __shared__ float s_red[256];

    const int g = blockIdx.x;
    const int tid = threadIdx.x;

    // ---- phase 0: pack node-MLP weights into MFMA B-fragment order (2 slots/thread)
    {
        int s0 = blockIdx.x * 256 + tid;
#pragma unroll
        for (int e = 0; e < 2; ++e) {
            int s = s0 + e * 32768;
            if (s < 32768) {                       // npW1: [128,256]
                const int p = s;
                const int j = p & 7, l = (p >> 3) & 63, kb = (p >> 9) & 3, ct = p >> 11;
                const int k = kb * 32 + ((l >> 4) << 3) + j;
                const int n = ct * 16 + (l & 15);
                wsb[PK_NPW1 + p] = __float2bfloat16(npW1[k * 256 + n]);
            } else if (s < 49152) {                // ppW1: [128,128]
                const int p = s - 32768;
                const int j = p & 7, l = (p >> 3) & 63, kb = (p >> 9) & 3, ct = p >> 11;
                const int k = kb * 32 + ((l >> 4) << 3) + j;
                const int n = ct * 16 + (l & 15);
                wsb[PK_PPW1 + p] = __float2bfloat16(ppW1[k * 128 + n]);
            } else if (s < 53248) {                // npW2: [256,12] -> padded N=16
                const int p = s - 49152;
                const int j = p & 7, l = (p >> 3) & 63, kb = p >> 9;
                const int k = kb * 32 + ((l >> 4) << 3) + j;
                const int n = l & 15;
                wsb[PK_NPW2 + p] = __float2bfloat16(n < 12 ? npW2[k * 12 + n] : 0.0f);
            } else if (s < 55296) {                // ppW2: [128,3] -> padded N=16
                const int p = s - 53248;
                const int j = p & 7, l = (p >> 3) & 63, kb = p >> 9;
                const int k = kb * 32 + ((l >> 4) << 3) + j;
                const int n = l & 15;
                wsb[PK_PPW2 + p] = __float2bfloat16(n < 3 ? ppW2[k * 3 + n] : 0.0f);
            }
        }
    }

    // ---- phase 1: time embedding (tid<128) + cond layer1 (tid in [128,192))
    if (tid < 128) {
        const float tval = t[g];
        const int i = tid & 63;
        const float fr = expf(-(float)i * 0.14619587892025688f);
        const float arg = tval * fr;
        s_te[tid] = (tid < 64) ? sinf(arg) : cosf(arg);
    } else if (tid < 192) {
        const int c = tid - 128;
        if (c < 32) {
            float acc = topob1[c];
            for (int k = 0; k < 7; ++k)
                acc += topo[g * 7 + k] * topoW1[k * 32 + c];
            s_l1[c] = silu_f(acc);
        } else if (c < 48) {
            const int j = c - 32;
            float acc = stabb1[j];
            for (int k = 0; k < 2; ++k)
                acc += stab[g * 2 + k] * stabW1[k * 16 + j];
            s_l1[c] = silu_f(acc);
        } else {
            const int j = c - 48;
            float acc = sustb1[j];
            for (int k = 0; k < 3; ++k)
                acc += sust[g * 3 + k] * sustW1[k * 16 + j];
            s_l1[c] = silu_f(acc);
        }
    }
    __syncthreads();

    // ---- phase 2: time MLP layer 1 [128]->[256], all threads, one col each
    {
        float acc = tmb1[tid];
#pragma unroll 4
        for (int k = 0; k < 128; ++k)
            acc += s_te[k] * tmW1[k * 256 + tid];
        s_th1[tid] = silu_f(acc);
    }
    __syncthreads();

    // ---- phase 3: time MLP layer 2 [256]->[128], split-k 2-way
    {
        const int j = tid & 127, half = tid >> 7;
        float acc = 0.0f;
#pragma unroll 4
        for (int kk = 0; kk < 128; ++kk)
            acc += s_th1[half * 128 + kk] * tmW2[(half * 128 + kk) * 128 + j];
        s_red[tid] = acc;
    }
    __syncthreads();

    // ---- phase 4: finish tef (tid<128) + cond layer2 (tid in [128,192))
    if (tid < 128) {
        s_tef[tid] = tmb2[tid] + s_red[tid] + s_red[tid + 128];
    } else if (tid < 192) {
        const int c = tid - 128;
        if (c < 32) {
            float acc = topob2[c];
            for (int k = 0; k < 32; ++k)
                acc += s_l1[k] * topoW2[k * 32 + c];
            s_cat[c] = acc;
        } else if (c < 48) {
            const int j = c - 32;
            float acc = stabb2[j];
            for (int k = 0; k < 16; ++k)
                acc += s_l1[32 + k] * stabW2[k * 16 + j];
            s_cat[c] = acc;
        } else {
            const int j = c - 48;
            float acc = sustb2[j];
            for (int k = 0; k < 16; ++k)
                acc += s_l1[48 + k] * sustW2[k * 16 + j];
            s_cat[c] = acc;
        }
    }
    __syncthreads();

    // ---- phase 5/6: comb layer 1 [64]->[64], split-k 4-way
    {
        const int j = tid & 63, part = tid >> 6;
        float acc = 0.0f;
#pragma unroll
        for (int kk = 0; kk < 16; ++kk)
            acc += s_cat[part * 16 + kk] * combW1[(part * 16 + kk) * 64 + j];
        s_red[tid] = acc;
    }
    __syncthreads();
    if (tid < 64)
        s_c1[tid] = silu_f(combb1[tid] + s_red[tid] + s_red[tid + 64] +
                           s_red[tid + 128] + s_red[tid + 192]);
    __syncthreads();

    // ---- phase 7/8: comb layer 2 [64]->[64], split-k 4-way
    {
        const int j = tid & 63, part = tid >> 6;
        float acc = 0.0f;
#pragma unroll
        for (int kk = 0; kk < 16; ++kk)
            acc += s_c1[part * 16 + kk] * combW2[(part * 16 + kk) * 64 + j];
        s_red[tid] = acc;
    }
    __syncthreads();
    if (tid < 64)
        s_cond[tid] = combb2[tid] + s_red[tid] + s_red[tid + 64] +
                      s_red[tid + 128] + s_red[tid + 192];
    __syncthreads();

    // ---- phase 9/10: v = cond @ Wv  [64]x[64,128], split-k 2-way
    {
        const int j = tid & 127, half = tid >> 7;
        float acc = 0.0f;
#pragma unroll
        for (int kk = 0; kk < 32; ++kk)
            acc += s_cond[half * 32 + kk] * Wv[(half * 32 + kk) * 128 + j];
        s_red[tid] = acc;
    }
    __syncthreads();
    if (tid < 128) s_v[tid] = s_red[tid] + s_red[tid + 128];
    __syncthreads();

    // ---- phase 11/12: a = v @ Wo + bo ; gadd = 6*(a + silu(tef))
    {
        const int j = tid & 127, half = tid >> 7;
        float acc = 0.0f;
#pragma unroll 4
        for (int kk = 0; kk < 64; ++kk)
            acc += s_v[half * 64 + kk] * Wo[(half * 64 + kk) * 128 + j];
        s_red[tid] = acc;
    }
    __syncthreads();
    if (tid < 128)
        gadd[g * 128 + tid] =
            6.0f * (bo[tid] + s_red[tid] + s_red[tid + 128] + silu_f(s_tef[tid]));
}

// ---------------------------------------------------------------------------
// Kernel 2: per-node output MLPs via MFMA.  64 nodes/block, 256 threads.
// MFMA contract (mfma_f32_16x16x32_bf16), q=lane>>4, r=lane&15:
//   A-frag: A[m=r][k=q*8+j]   B-frag: B[k=q*8+j][n=r]   D: D[m=q*4+i][n=r]
// ---------------------------------------------------------------------------
__global__ __launch_bounds__(256) void node_kernel(
        const float* __restrict__ x, const int* __restrict__ batch,
        const float* __restrict__ Wn, const float* __restrict__ bn,
        const float* __restrict__ npb1, const float* __restrict__ npb2,
        const float* __restrict__ ppb1, const float* __restrict__ ppb2,
        const float* __restrict__ gadd, const hbf16* __restrict__ wsb,
        float* __restrict__ out) {
    __shared__ __align__(16) hbf16 hA[BN * 136];   // h bf16, row pad 136 (2-way bank alias)
    __shared__ __align__(16) hbf16 zs[BN * 264];   // hidden activations (np: stride 264, pp: 136)

    const int nb = blockIdx.x * BN;
    const int tid = threadIdx.x;
    const int lane = tid & 63;
    const int w = tid >> 6;
    const int q = lane >> 4;
    const int r = lane & 15;

    // ---- P1: h[n][d] = bn[d] + gadd[batch[n]][d] + x[n]@Wn ; store bf16 to hA
    for (int idx = tid; idx < BN * 128; idx += 256) {
        const int nl = idx >> 7;
        const int d  = idx & 127;
        const int gn = nb + nl;
        float acc = 0.0f;
        if (gn < NN) {
            const int b = batch[gn];
            acc = bn[d] + gadd[b * 128 + d];
#pragma unroll
            for (int k = 0; k < 12; ++k)
                acc += x[gn * 12 + k] * Wn[k * 128 + d];
        }
        hA[nl * 136 + d] = __float2bfloat16(acc);
    }
    __syncthreads();

    // ---- P2: z1 = silu(h @ npW1 + npb1)  -> zs (bf16), wave w owns cols [64w,64w+64)
    {
        f32x4_t acc[4][4];
#pragma unroll
        for (int ci = 0; ci < 4; ++ci)
#pragma unroll
            for (int rt = 0; rt < 4; ++rt) acc[ci][rt] = (f32x4_t){0.f, 0.f, 0.f, 0.f};

        for (int kb = 0; kb < 4; ++kb) {
            bf16x8_t Af[4];
#pragma unroll
            for (int rt = 0; rt < 4; ++rt)
                Af[rt] = *reinterpret_cast<const bf16x8_t*>(
                    &hA[(rt * 16 + r) * 136 + kb * 32 + q * 8]);
#pragma unroll
            for (int ci = 0; ci < 4; ++ci) {
                const int ct = w * 4 + ci;
                bf16x8_t Bf = *reinterpret_cast<const bf16x8_t*>(
                    &wsb[PK_NPW1 + ((ct * 4 + kb) * 64 + lane) * 8]);
#pragma unroll
                for (int rt = 0; rt < 4; ++rt)
                    acc[ci][rt] = __builtin_amdgcn_mfma_f32_16x16x32_bf16(
                        Af[rt], Bf, acc[ci][rt], 0, 0, 0);
            }
        }
#pragma unroll
        for (int ci = 0; ci < 4; ++ci) {
            const int col = (w * 4 + ci) * 16 + r;
            const float b1 = npb1[col];
#pragma unroll
            for (int rt = 0; rt < 4; ++rt) {
#pragma unroll
                for (int i = 0; i < 4; ++i) {
                    const int m = rt * 16 + q * 4 + i;
                    zs[m * 264 + col] = __float2bfloat16(silu_f(acc[ci][rt][i] + b1));
                }
            }
        }
    }
    __syncthreads();

    // ---- P3: node_pred = z1 @ npW2 + npb2 ; wave w owns node rows [16w,16w+16)
    {
        f32x4_t acc2 = (f32x4_t){0.f, 0.f, 0.f, 0.f};
        for (int kb = 0; kb < 8; ++kb) {
            bf16x8_t Af = *reinterpret_cast<const bf16x8_t*>(
                &zs[(w * 16 + r) * 264 + kb * 32 + q * 8]);
            bf16x8_t Bf = *reinterpret_cast<const bf16x8_t*>(
                &wsb[PK_NPW2 + (kb * 64 + lane) * 8]);
            acc2 = __builtin_amdgcn_mfma_f32_16x16x32_bf16(Af, Bf, acc2, 0, 0, 0);
        }
        if (r < 12) {
            const float b2 = npb2[r];
#pragma unroll
            for (int i = 0; i < 4; ++i) {
                const int gn = nb + w * 16 + q * 4 + i;
                if (gn < NN) out[gn * 12 + r] = acc2[i] + b2;
            }
        }
    }
    __syncthreads();

    // ---- P4: z2 = silu(h @ ppW1 + ppb1) -> zs (stride 136), wave w owns cols [32w,32w+32)
    {
        f32x4_t acc[2][4];
#pragma unroll
        for (int ci = 0; ci < 2; ++ci)
#pragma unroll
            for (int rt = 0; rt < 4; ++rt) acc[ci][rt] = (f32x4_t){0.f, 0.f, 0.f, 0.f};

        for (int kb = 0; kb < 4; ++kb) {
            bf16x8_t Af[4];
#pragma unroll
            for (int rt = 0; rt < 4; ++rt)
                Af[rt] = *reinterpret_cast<const bf16x8_t*>(
                    &hA[(rt * 16 + r) * 136 + kb * 32 + q * 8]);
#pragma unroll
            for (int ci = 0; ci < 2; ++ci) {
                const int ct = w * 2 + ci;
                bf16x8_t Bf = *reinterpret_cast<const bf16x8_t*>(
                    &wsb[PK_PPW1 + ((ct * 4 + kb) * 64 + lane) * 8]);
#pragma unroll
                for (int rt = 0; rt < 4; ++rt)
                    acc[ci][rt] = __builtin_amdgcn_mfma_f32_16x16x32_bf16(
                        Af[rt], Bf, acc[ci][rt], 0, 0, 0);
            }
        }
        __syncthreads();   // zs (np layout) fully consumed in P3; safe to overwrite
#pragma unroll
        for (int ci = 0; ci < 2; ++ci) {
            const int col = (w * 2 + ci) * 16 + r;
            const float b1 = ppb1[col];
#pragma unroll
            for (int rt = 0; rt < 4; ++rt) {
#pragma unroll
                for (int i = 0; i < 4; ++i) {
                    const int m = rt * 16 + q * 4 + i;
                    zs[m * 136 + col] = __float2bfloat16(silu_f(acc[ci][rt][i] + b1));
                }
            }
        }
    }
    __syncthreads();

    // ---- P5: pos_pred = z2 @ ppW2 + ppb2 ; wave w owns node rows [16w,16w+16)
    {
        f32x4_t acc2 = (f32x4_t){0.f, 0.f, 0.f, 0.f};
        for (int kb = 0; kb < 4; ++kb) {
            bf16x8_t Af = *reinterpret_cast<const bf16x8_t*>(
                &zs[(w * 16 + r) * 136 + kb * 32 + q * 8]);
            bf16x8_t Bf = *reinterpret_cast<const bf16x8_t*>(
                &wsb[PK_PPW2 + (kb * 64 + lane) * 8]);
            acc2 = __builtin_amdgcn_mfma_f32_16x16x32_bf16(Af, Bf, acc2, 0, 0, 0);
        }
        if (r < 3) {
            const float b2 = ppb2[r];
#pragma unroll
            for (int i = 0; i < 4; ++i) {
                const int gn = nb + w * 16 + q * 4 + i;
                if (gn < NN) out[NN * 12 + gn * 3 + r] = acc2[i] + b2;
            }
        }
    }
}

// ---------------------------------------------------------------------------
extern "C" void kernel_launch(void* const* d_in, const int* in_sizes, int n_in,
                              void* d_out, int out_size, void* d_ws, size_t ws_size,
                              hipStream_t stream) {
    const float* x      = (const float*)d_in[0];
    const float* t      = (const float*)d_in[4];
    const float* topo   = (const float*)d_in[5];
    const float* stab   = (const float*)d_in[6];
    const float* sust   = (const float*)d_in[7];
    const int*   batch  = (const int*)d_in[8];
    const float* Wn     = (const float*)d_in[9];
    const float* bn     = (const float*)d_in[10];
    const float* tmW1   = (const float*)d_in[13];
    const float* tmb1   = (const float*)d_in[14];
    const float* tmW2   = (const float*)d_in[15];
    const float* tmb2   = (const float*)d_in[16];
    const float* topoW1 = (const float*)d_in[17];
    const float* topob1 = (const float*)d_in[18];
    const float* topoW2 = (const float*)d_in[19];
    const float* topob2 = (const float*)d_in[20];
    const float* stabW1 = (const float*)d_in[21];
    const float* stabb1 = (const float*)d_in[22];
    const float* stabW2 = (const float*)d_in[23];
    const float* stabb2 = (const float*)d_in[24];
    const float* sustW1 = (const float*)d_in[25];
    const float* sustb1 = (const float*)d_in[26];
    const float* sustW2 = (const float*)d_in[27];
    const float* sustb2 = (const float*)d_in[28];
    const float* combW1 = (const float*)d_in[29];
    const float* combb1 = (const float*)d_in[30];
    const float* combW2 = (const float*)d_in[31];
    const float* combb2 = (const float*)d_in[32];
    const float* Wv     = (const float*)d_in[35];
    const float* Wo     = (const float*)d_in[36];
    const float* bo     = (const float*)d_in[37];
    const float* npW1   = (const float*)d_in[44];
    const float* npb1   = (const float*)d_in[45];
    const float* npW2   = (const float*)d_in[46];
    const float* npb2   = (const float*)d_in[47];
    const float* ppW1   = (const float*)d_in[48];
    const float* ppb1   = (const float*)d_in[49];
    const float* ppW2   = (const float*)d_in[50];
    const float* ppb2   = (const float*)d_in[51];

    float* gadd = (float*)d_ws;
    hbf16* wsb  = (hbf16*)d_ws;
    float* out  = (float*)d_out;

    graph_kernel<<<GG, 256, 0, stream>>>(t, topo, stab, sust,
                                         tmW1, tmb1, tmW2, tmb2,
                                         topoW1, topob1, topoW2, topob2,
                                         stabW1, stabb1, stabW2, stabb2,
                                         sustW1, sustb1, sustW2, sustb2,
                                         combW1, combb1, combW2, combb2,
                                         Wv, Wo, bo,
                                         npW1, npW2, ppW1, ppW2,
                                         gadd, wsb);

    node_kernel<<<(NN + BN - 1) / BN, 256, 0, stream>>>(
        x, batch, Wn, bn, npb1, npb2, ppb1, ppb2, gadd, wsb, out);
}

// Round 4
// 232.625 us; speedup vs baseline: 1.1858x; 1.0067x over previous
//
#include <hip/hip_runtime.h>
#include <hip/hip_bf16.h>

#define NN 20000
#define GG 128

typedef __bf16 bf16x8_t __attribute__((ext_vector_type(8)));
typedef float  f32x4_t  __attribute__((ext_vector_type(4)));
typedef __hip_bfloat16 hbf16;

// ws layout (bf16-element offsets from (hbf16*)d_ws):
//   bytes [0, 65536) : gadd fp32 [128][128]
#define PK_NPW1 32768   // 32768 : npW1 B-frags (16 ct x 4 kb x 64 lane x 8)
#define PK_PPW1 65536   // 16384 : ppW1 (8 ct x 4 kb x 64 x 8)
#define PK_NPW2 81920   //  4096 : npW2 (8 kb x 64 x 8), cols>=12 zero
#define PK_PPW2 86016   //  2048 : ppW2 (4 kb x 64 x 8), cols>=3 zero
#define PK_WN   88064   //  4096 : Wn   (8 ct x 1 kb x 64 x 8), K padded 12->32

__device__ __forceinline__ float silu_f(float v) {
    return v / (1.0f + expf(-v));
}

// ---------------------------------------------------------------------------
// Kernel 1: per-graph pipeline + distributed weight fragment packing.
// 128 blocks x 256 threads.
// ---------------------------------------------------------------------------
__global__ __launch_bounds__(256) void graph_kernel(
        const float* __restrict__ t, const float* __restrict__ topo,
        const float* __restrict__ stab, const float* __restrict__ sust,
        const float* __restrict__ tmW1, const float* __restrict__ tmb1,
        const float* __restrict__ tmW2, const float* __restrict__ tmb2,
        const float* __restrict__ topoW1, const float* __restrict__ topob1,
        const float* __restrict__ topoW2, const float* __restrict__ topob2,
        const float* __restrict__ stabW1, const float* __restrict__ stabb1,
        const float* __restrict__ stabW2, const float* __restrict__ stabb2,
        const float* __restrict__ sustW1, const float* __restrict__ sustb1,
        const float* __restrict__ sustW2, const float* __restrict__ sustb2,
        const float* __restrict__ combW1, const float* __restrict__ combb1,
        const float* __restrict__ combW2, const float* __restrict__ combb2,
        const float* __restrict__ Wv, const float* __restrict__ Wo,
        const float* __restrict__ bo,
        const float* __restrict__ npW1, const float* __restrict__ npW2,
        const float* __restrict__ ppW1, const float* __restrict__ ppW2,
        const float* __restrict__ Wn,
        float* __restrict__ gadd, hbf16* __restrict__ wsb) {
    __shared__ float s_te[128];
    __shared__ float s_th1[256];
    __shared__ float s_tef[128];
    __shared__ float s_l1[64];
    __shared__ float s_cat[64];
    __shared__ float s_c1[64];
    __shared__ float s_cond[64];
    __shared__ float s_v[128];
    __shared__ float s_red[256];

    const int g = blockIdx.x;
    const int tid = threadIdx.x;

    // ---- phase 0: pack weights into MFMA B-fragment order (distributed: 512/block)
    {
#pragma unroll
        for (int e = 0; e < 2; ++e) {
            const int s = blockIdx.x * 512 + e * 256 + tid;
            if (s < 32768) {                       // npW1: [128,256]
                const int p = s;
                const int j = p & 7, l = (p >> 3) & 63, kb = (p >> 9) & 3, ct = p >> 11;
                const int k = kb * 32 + ((l >> 4) << 3) + j;
                const int n = ct * 16 + (l & 15);
                wsb[PK_NPW1 + p] = __float2bfloat16(npW1[k * 256 + n]);
            } else if (s < 49152) {                // ppW1: [128,128]
                const int p = s - 32768;
                const int j = p & 7, l = (p >> 3) & 63, kb = (p >> 9) & 3, ct = p >> 11;
                const int k = kb * 32 + ((l >> 4) << 3) + j;
                const int n = ct * 16 + (l & 15);
                wsb[PK_PPW1 + p] = __float2bfloat16(ppW1[k * 128 + n]);
            } else if (s < 53248) {                // npW2: [256,12] -> padded N=16
                const int p = s - 49152;
                const int j = p & 7, l = (p >> 3) & 63, kb = p >> 9;
                const int k = kb * 32 + ((l >> 4) << 3) + j;
                const int n = l & 15;
                wsb[PK_NPW2 + p] = __float2bfloat16(n < 12 ? npW2[k * 12 + n] : 0.0f);
            } else if (s < 55296) {                // ppW2: [128,3] -> padded N=16
                const int p = s - 53248;
                const int j = p & 7, l = (p >> 3) & 63, kb = p >> 9;
                const int k = kb * 32 + ((l >> 4) << 3) + j;
                const int n = l & 15;
                wsb[PK_PPW2 + p] = __float2bfloat16(n < 3 ? ppW2[k * 3 + n] : 0.0f);
            } else if (s < 59392) {                // Wn: [12,128] -> K padded to 32
                const int p = s - 55296;
                const int j = p & 7, l = (p >> 3) & 63, ct = p >> 9;
                const int k = ((l >> 4) << 3) + j;
                const int n = ct * 16 + (l & 15);
                wsb[PK_WN + p] = __float2bfloat16(k < 12 ? Wn[k * 128 + n] : 0.0f);
            }
        }
    }

    // ---- phase 1: time embedding (tid<128) + cond layer1 (tid in [128,192))
    if (tid < 128) {
        const float tval = t[g];
        const int i = tid & 63;
        const float fr = expf(-(float)i * 0.14619587892025688f);
        const float arg = tval * fr;
        s_te[tid] = (tid < 64) ? sinf(arg) : cosf(arg);
    } else if (tid < 192) {
        const int c = tid - 128;
        if (c < 32) {
            float acc = topob1[c];
            for (int k = 0; k < 7; ++k)
                acc += topo[g * 7 + k] * topoW1[k * 32 + c];
            s_l1[c] = silu_f(acc);
        } else if (c < 48) {
            const int j = c - 32;
            float acc = stabb1[j];
            for (int k = 0; k < 2; ++k)
                acc += stab[g * 2 + k] * stabW1[k * 16 + j];
            s_l1[c] = silu_f(acc);
        } else {
            const int j = c - 48;
            float acc = sustb1[j];
            for (int k = 0; k < 3; ++k)
                acc += sust[g * 3 + k] * sustW1[k * 16 + j];
            s_l1[c] = silu_f(acc);
        }
    }
    __syncthreads();

    // ---- phase 2: time MLP layer 1 [128]->[256]
    {
        float acc = tmb1[tid];
#pragma unroll 4
        for (int k = 0; k < 128; ++k)
            acc += s_te[k] * tmW1[k * 256 + tid];
        s_th1[tid] = silu_f(acc);
    }
    __syncthreads();

    // ---- phase 3: time MLP layer 2 [256]->[128], split-k 2-way
    {
        const int j = tid & 127, half = tid >> 7;
        float acc = 0.0f;
#pragma unroll 4
        for (int kk = 0; kk < 128; ++kk)
            acc += s_th1[half * 128 + kk] * tmW2[(half * 128 + kk) * 128 + j];
        s_red[tid] = acc;
    }
    __syncthreads();

    // ---- phase 4: finish tef + cond layer2
    if (tid < 128) {
        s_tef[tid] = tmb2[tid] + s_red[tid] + s_red[tid + 128];
    } else if (tid < 192) {
        const int c = tid - 128;
        if (c < 32) {
            float acc = topob2[c];
            for (int k = 0; k < 32; ++k)
                acc += s_l1[k] * topoW2[k * 32 + c];
            s_cat[c] = acc;
        } else if (c < 48) {
            const int j = c - 32;
            float acc = stabb2[j];
            for (int k = 0; k < 16; ++k)
                acc += s_l1[32 + k] * stabW2[k * 16 + j];
            s_cat[c] = acc;
        } else {
            const int j = c - 48;
            float acc = sustb2[j];
            for (int k = 0; k < 16; ++k)
                acc += s_l1[48 + k] * sustW2[k * 16 + j];
            s_cat[c] = acc;
        }
    }
    __syncthreads();

    // ---- comb layer 1 [64]->[64], split-k 4-way
    {
        const int j = tid & 63, part = tid >> 6;
        float acc = 0.0f;
#pragma unroll
        for (int kk = 0; kk < 16; ++kk)
            acc += s_cat[part * 16 + kk] * combW1[(part * 16 + kk) * 64 + j];
        s_red[tid] = acc;
    }
    __syncthreads();
    if (tid < 64)
        s_c1[tid] = silu_f(combb1[tid] + s_red[tid] + s_red[tid + 64] +
                           s_red[tid + 128] + s_red[tid + 192]);
    __syncthreads();

    // ---- comb layer 2 [64]->[64], split-k 4-way
    {
        const int j = tid & 63, part = tid >> 6;
        float acc = 0.0f;
#pragma unroll
        for (int kk = 0; kk < 16; ++kk)
            acc += s_c1[part * 16 + kk] * combW2[(part * 16 + kk) * 64 + j];
        s_red[tid] = acc;
    }
    __syncthreads();
    if (tid < 64)
        s_cond[tid] = combb2[tid] + s_red[tid] + s_red[tid + 64] +
                      s_red[tid + 128] + s_red[tid + 192];
    __syncthreads();

    // ---- v = cond @ Wv, split-k 2-way
    {
        const int j = tid & 127, half = tid >> 7;
        float acc = 0.0f;
#pragma unroll
        for (int kk = 0; kk < 32; ++kk)
            acc += s_cond[half * 32 + kk] * Wv[(half * 32 + kk) * 128 + j];
        s_red[tid] = acc;
    }
    __syncthreads();
    if (tid < 128) s_v[tid] = s_red[tid] + s_red[tid + 128];
    __syncthreads();

    // ---- a = v @ Wo + bo ; gadd = 6*(a + silu(tef))
    {
        const int j = tid & 127, half = tid >> 7;
        float acc = 0.0f;
#pragma unroll 4
        for (int kk = 0; kk < 64; ++kk)
            acc += s_v[half * 64 + kk] * Wo[(half * 64 + kk) * 128 + j];
        s_red[tid] = acc;
    }
    __syncthreads();
    if (tid < 128)
        gadd[g * 128 + tid] =
            6.0f * (bo[tid] + s_red[tid] + s_red[tid + 128] + silu_f(s_tef[tid]));
}

// ---------------------------------------------------------------------------
// Kernel 2: barrier-free per-node MLPs.  Wave-autonomous: each wave owns 16
// nodes end-to-end.  256 threads = 4 independent waves; NO __syncthreads.
// MFMA contract (16x16x32 bf16), q=lane>>4, r=lane&15:
//   A[m=r][k=q*8+j]   B[k=q*8+j][n=r]   D[m=q*4+i][n=r]
// ---------------------------------------------------------------------------
__global__ __launch_bounds__(256, 1) void node_kernel(
        const float* __restrict__ x, const int* __restrict__ batch,
        const float* __restrict__ bn,
        const float* __restrict__ npb1, const float* __restrict__ npb2,
        const float* __restrict__ ppb1, const float* __restrict__ ppb2,
        const float* __restrict__ gadd, const hbf16* __restrict__ wsb,
        float* __restrict__ out) {
    // per-wave private LDS (no cross-wave sharing -> no barriers)
    __shared__ __align__(16) hbf16 z1s[4 * 16 * 264];  // z1 transpose buf
    __shared__ __align__(16) hbf16 hs[4 * 16 * 136];   // h / z2 transpose buf

    const int tid  = threadIdx.x;
    const int w    = tid >> 6;
    const int lane = tid & 63;
    const int q    = lane >> 4;
    const int r    = lane & 15;
    const int n16  = blockIdx.x * 64 + w * 16;   // first node of this wave

    hbf16* wz1 = z1s + w * (16 * 264);
    hbf16* wh  = hs  + w * (16 * 136);

    // ---- A-frag of x (M=16 nodes, K=12 padded to 32)
    bf16x8_t Ax;
    {
        const int node = n16 + r;
        float xv[8];
#pragma unroll
        for (int j = 0; j < 8; ++j) xv[j] = 0.0f;
        if (node < NN) {
            if (q == 0) {
                const float4 a = *reinterpret_cast<const float4*>(x + node * 12);
                const float4 b = *reinterpret_cast<const float4*>(x + node * 12 + 4);
                xv[0] = a.x; xv[1] = a.y; xv[2] = a.z; xv[3] = a.w;
                xv[4] = b.x; xv[5] = b.y; xv[6] = b.z; xv[7] = b.w;
            } else if (q == 1) {
                const float4 a = *reinterpret_cast<const float4*>(x + node * 12 + 8);
                xv[0] = a.x; xv[1] = a.y; xv[2] = a.z; xv[3] = a.w;
            }
        }
#pragma unroll
        for (int j = 0; j < 8; ++j) {
            const hbf16 tv = __float2bfloat16(xv[j]);
            Ax[j] = *reinterpret_cast<const __bf16*>(&tv);
        }
    }

    // ---- batch indices for the 4 node-rows this lane owns in D-layout
    int bidx[4];
#pragma unroll
    for (int i = 0; i < 4; ++i) {
        const int gn = n16 + q * 4 + i;
        bidx[i] = (gn < NN) ? batch[gn] : 0;
    }

    // ---- h = x@Wn (MFMA) + bn + gadd[batch]   (8 column tiles of 16)
    f32x4_t hacc[8];
#pragma unroll
    for (int ct = 0; ct < 8; ++ct) {
        const bf16x8_t Bf = *reinterpret_cast<const bf16x8_t*>(
            &wsb[PK_WN + (ct * 64 + lane) * 8]);
        hacc[ct] = __builtin_amdgcn_mfma_f32_16x16x32_bf16(
            Ax, Bf, (f32x4_t){0.f, 0.f, 0.f, 0.f}, 0, 0, 0);
    }
#pragma unroll
    for (int ct = 0; ct < 8; ++ct) {
        const int n = ct * 16 + r;
        const float bv = bn[n];
#pragma unroll
        for (int i = 0; i < 4; ++i) {
            const float hv = hacc[ct][i] + bv + gadd[bidx[i] * 128 + n];
            wh[(q * 4 + i) * 136 + n] = __float2bfloat16(hv);
        }
    }

    // ---- read h back as A-frags (K=128 -> 4 kb)
    bf16x8_t Ah[4];
#pragma unroll
    for (int kb = 0; kb < 4; ++kb)
        Ah[kb] = *reinterpret_cast<const bf16x8_t*>(
            &wh[r * 136 + kb * 32 + q * 8]);

    // ---- np L1: z1 = silu(h @ npW1 + npb1)   [16,128]x[128,256]
    {
        f32x4_t acc[16];
#pragma unroll
        for (int ct = 0; ct < 16; ++ct) acc[ct] = (f32x4_t){0.f, 0.f, 0.f, 0.f};
#pragma unroll
        for (int kb = 0; kb < 4; ++kb) {
#pragma unroll
            for (int ct = 0; ct < 16; ++ct) {
                const bf16x8_t Bf = *reinterpret_cast<const bf16x8_t*>(
                    &wsb[PK_NPW1 + ((ct * 4 + kb) * 64 + lane) * 8]);
                acc[ct] = __builtin_amdgcn_mfma_f32_16x16x32_bf16(
                    Ah[kb], Bf, acc[ct], 0, 0, 0);
            }
        }
#pragma unroll
        for (int ct = 0; ct < 16; ++ct) {
            const int col = ct * 16 + r;
            const float b1 = npb1[col];
#pragma unroll
            for (int i = 0; i < 4; ++i)
                wz1[(q * 4 + i) * 264 + col] =
                    __float2bfloat16(silu_f(acc[ct][i] + b1));
        }
    }

    // ---- np L2: node_pred = z1 @ npW2 + npb2   (K=256 -> 8 kb)
    {
        f32x4_t acc2 = (f32x4_t){0.f, 0.f, 0.f, 0.f};
#pragma unroll
        for (int kb = 0; kb < 8; ++kb) {
            const bf16x8_t Af = *reinterpret_cast<const bf16x8_t*>(
                &wz1[r * 264 + kb * 32 + q * 8]);
            const bf16x8_t Bf = *reinterpret_cast<const bf16x8_t*>(
                &wsb[PK_NPW2 + (kb * 64 + lane) * 8]);
            acc2 = __builtin_amdgcn_mfma_f32_16x16x32_bf16(Af, Bf, acc2, 0, 0, 0);
        }
        if (r < 12) {
            const float b2 = npb2[r];
#pragma unroll
            for (int i = 0; i < 4; ++i) {
                const int gn = n16 + q * 4 + i;
                if (gn < NN) out[gn * 12 + r] = acc2[i] + b2;
            }
        }
    }

    // ---- pp L1: z2 = silu(h @ ppW1 + ppb1)   [16,128]x[128,128]
    {
        f32x4_t acc[8];
#pragma unroll
        for (int ct = 0; ct < 8; ++ct) acc[ct] = (f32x4_t){0.f, 0.f, 0.f, 0.f};
#pragma unroll
        for (int kb = 0; kb < 4; ++kb) {
#pragma unroll
            for (int ct = 0; ct < 8; ++ct) {
                const bf16x8_t Bf = *reinterpret_cast<const bf16x8_t*>(
                    &wsb[PK_PPW1 + ((ct * 4 + kb) * 64 + lane) * 8]);
                acc[ct] = __builtin_amdgcn_mfma_f32_16x16x32_bf16(
                    Ah[kb], Bf, acc[ct], 0, 0, 0);
            }
        }
        // overwrite h region with z2 (h already consumed into Ah regs;
        // same-wave LDS ops are in-order, so no barrier needed)
#pragma unroll
        for (int ct = 0; ct < 8; ++ct) {
            const int col = ct * 16 + r;
            const float b1 = ppb1[col];
#pragma unroll
            for (int i = 0; i < 4; ++i)
                wh[(q * 4 + i) * 136 + col] =
                    __float2bfloat16(silu_f(acc[ct][i] + b1));
        }
    }

    // ---- pp L2: pos_pred = z2 @ ppW2 + ppb2   (K=128 -> 4 kb)
    {
        f32x4_t acc2 = (f32x4_t){0.f, 0.f, 0.f, 0.f};
#pragma unroll
        for (int kb = 0; kb < 4; ++kb) {
            const bf16x8_t Af = *reinterpret_cast<const bf16x8_t*>(
                &wh[r * 136 + kb * 32 + q * 8]);
            const bf16x8_t Bf = *reinterpret_cast<const bf16x8_t*>(
                &wsb[PK_PPW2 + (kb * 64 + lane) * 8]);
            acc2 = __builtin_amdgcn_mfma_f32_16x16x32_bf16(Af, Bf, acc2, 0, 0, 0);
        }
        if (r < 3) {
            const float b2 = ppb2[r];
#pragma unroll
            for (int i = 0; i < 4; ++i) {
                const int gn = n16 + q * 4 + i;
                if (gn < NN) out[NN * 12 + gn * 3 + r] = acc2[i] + b2;
            }
        }
    }
}

// ---------------------------------------------------------------------------
extern "C" void kernel_launch(void* const* d_in, const int* in_sizes, int n_in,
                              void* d_out, int out_size, void* d_ws, size_t ws_size,
                              hipStream_t stream) {
    const float* x      = (const float*)d_in[0];
    const float* t      = (const float*)d_in[4];
    const float* topo   = (const float*)d_in[5];
    const float* stab   = (const float*)d_in[6];
    const float* sust   = (const float*)d_in[7];
    const int*   batch  = (const int*)d_in[8];
    const float* Wn     = (const float*)d_in[9];
    const float* bn     = (const float*)d_in[10];
    const float* tmW1   = (const float*)d_in[13];
    const float* tmb1   = (const float*)d_in[14];
    const float* tmW2   = (const float*)d_in[15];
    const float* tmb2   = (const float*)d_in[16];
    const float* topoW1 = (const float*)d_in[17];
    const float* topob1 = (const float*)d_in[18];
    const float* topoW2 = (const float*)d_in[19];
    const float* topob2 = (const float*)d_in[20];
    const float* stabW1 = (const float*)d_in[21];
    const float* stabb1 = (const float*)d_in[22];
    const float* stabW2 = (const float*)d_in[23];
    const float* stabb2 = (const float*)d_in[24];
    const float* sustW1 = (const float*)d_in[25];
    const float* sustb1 = (const float*)d_in[26];
    const float* sustW2 = (const float*)d_in[27];
    const float* sustb2 = (const float*)d_in[28];
    const float* combW1 = (const float*)d_in[29];
    const float* combb1 = (const float*)d_in[30];
    const float* combW2 = (const float*)d_in[31];
    const float* combb2 = (const float*)d_in[32];
    const float* Wv     = (const float*)d_in[35];
    const float* Wo     = (const float*)d_in[36];
    const float* bo     = (const float*)d_in[37];
    const float* npW1   = (const float*)d_in[44];
    const float* npb1   = (const float*)d_in[45];
    const float* npW2   = (const float*)d_in[46];
    const float* npb2   = (const float*)d_in[47];
    const float* ppW1   = (const float*)d_in[48];
    const float* ppb1   = (const float*)d_in[49];
    const float* ppW2   = (const float*)d_in[50];
    const float* ppb2   = (const float*)d_in[51];

    float* gadd = (float*)d_ws;
    hbf16* wsb  = (hbf16*)d_ws;
    float* out  = (float*)d_out;

    graph_kernel<<<GG, 256, 0, stream>>>(t, topo, stab, sust,
                                         tmW1, tmb1, tmW2, tmb2,
                                         topoW1, topob1, topoW2, topob2,
                                         stabW1, stabb1, stabW2, stabb2,
                                         sustW1, sustb1, sustW2, sustb2,
                                         combW1, combb1, combW2, combb2,
                                         Wv, Wo, bo,
                                         npW1, npW2, ppW1, ppW2, Wn,
                                         gadd, wsb);

    node_kernel<<<(NN + 63) / 64, 256, 0, stream>>>(
        x, batch, bn, npb1, npb2, ppb1, ppb2, gadd, wsb, out);
}